// Round 3
// baseline (222.337 us; speedup 1.0000x reference)
//
#include <hip/hip_runtime.h>
#include <hip/hip_bf16.h>

#define BB 8
#define NN 2048
#define FIN 128
#define FO 64
#define ALPHA 0.2f

typedef __attribute__((ext_vector_type(8))) short bf16x8;
typedef __attribute__((ext_vector_type(4))) float f32x4;
typedef __attribute__((ext_vector_type(4))) int i32x4;

typedef __attribute__((address_space(1))) const void gvoid;
typedef __attribute__((address_space(3))) void lvoid;

__device__ inline void gl_lds16(const void* g, void* l) {
    // async global->LDS DMA, 16B/lane; LDS dest = wave-uniform base + lane*16
    __builtin_amdgcn_global_load_lds((gvoid*)g, (lvoid*)l, 16, 0, 0);
}

__device__ inline short f2bf(float x) {
    unsigned u = __float_as_uint(x);
    u += 0x7fffu + ((u >> 16) & 1u);   // RNE
    return (short)(u >> 16);
}

// ---------------- Kernel A: Wh = h@W; whF in MFMA B-fragment layout ----------
// whF[b][jc][ot][L][8]: lane L holds Wh[b][j=jc*32+(L>>4)*8+jj][o=ot*16+(L&15)]
__global__ __launch_bounds__(256) void wh_kernel(
    const float* __restrict__ h, const float* __restrict__ W,
    const float* __restrict__ a, float* __restrict__ e1, float* __restrict__ e2,
    short* __restrict__ whF)
{
    __shared__ float hs[32][FIN];
    const int r0 = blockIdx.x * 32;
    const int t = threadIdx.x;
    const float4* hsrc = (const float4*)(h + (size_t)r0 * FIN);
    float4* hdst = (float4*)(&hs[0][0]);
#pragma unroll
    for (int k = 0; k < 4; k++) hdst[t + 256 * k] = hsrc[t + 256 * k];
    __syncthreads();

    const int o = t & 63;
    const int wv = t >> 6;
    float acc[8];
#pragma unroll
    for (int rr = 0; rr < 8; rr++) acc[rr] = 0.f;

    for (int f = 0; f < FIN; f += 4) {
        const float w0 = W[(f + 0) * FO + o];
        const float w1 = W[(f + 1) * FO + o];
        const float w2 = W[(f + 2) * FO + o];
        const float w3 = W[(f + 3) * FO + o];
#pragma unroll
        for (int rr = 0; rr < 8; rr++) {
            float4 hv = *(const float4*)&hs[wv * 8 + rr][f];
            acc[rr] = fmaf(hv.x, w0, acc[rr]);
            acc[rr] = fmaf(hv.y, w1, acc[rr]);
            acc[rr] = fmaf(hv.z, w2, acc[rr]);
            acc[rr] = fmaf(hv.w, w3, acc[rr]);
        }
    }

    const int b   = r0 / NN;
    const int ib0 = r0 - b * NN;
    const int ibb = ib0 + wv * 8;
    const int jc  = ibb >> 5;
    const int qq  = (ibb >> 3) & 3;
    const int ot  = o >> 4, mm = o & 15;
    const int L   = mm + qq * 16;
    bf16x8 frag;
#pragma unroll
    for (int rr = 0; rr < 8; rr++) frag[rr] = f2bf(acc[rr]);
    *(bf16x8*)(whF + ((((size_t)(b * 64 + jc) * 4 + ot) * 64 + L) * 8)) = frag;

    const float a1 = a[o], a2 = a[FO + o];
#pragma unroll
    for (int rr = 0; rr < 8; rr++) {
        float v1 = acc[rr] * a1, v2 = acc[rr] * a2;
#pragma unroll
        for (int msk = 32; msk >= 1; msk >>= 1) {
            v1 += __shfl_xor(v1, msk, 64);
            v2 += __shfl_xor(v2, msk, 64);
        }
        if (o == 0) { e1[r0 + wv * 8 + rr] = v1; e2[r0 + wv * 8 + rr] = v2; }
    }
}

// ---------------- Kernel A2: e2max per batch --------------------------------
__global__ __launch_bounds__(256) void e2max_kernel(
    const float* __restrict__ e2, float* __restrict__ e2max)
{
    const int b = blockIdx.x;
    const int t = threadIdx.x;
    float m = -1e30f;
    for (int j = t; j < NN; j += 256) m = fmaxf(m, e2[b * NN + j]);
#pragma unroll
    for (int k = 32; k >= 1; k >>= 1) m = fmaxf(m, __shfl_xor(m, k, 64));
    __shared__ float red[4];
    if ((t & 63) == 0) red[t >> 6] = m;
    __syncthreads();
    if (t == 0) e2max[b] = fmaxf(fmaxf(red[0], red[1]), fmaxf(red[2], red[3]));
}

// ---------------- Kernel B: barrier-free pipelined fused attention ----------
// block = (b, 16-row i-tile); wave w privately owns j-slice [w*512, w*512+512).
// Quad-buffered global_load_lds staging, explicit vmcnt, no __syncthreads in
// the K-loop. 5th MFMA vs ones-fragment produces the softmax denominator from
// the SAME truncated p-hat as the numerator (truncation bias cancels).
struct SMemS {
    int   adjs[4][4][16][8][4];   // [wave][buf][row][unit16B][4 ints] = 32 KB
    float e2s[4][512];            // 8 KB
};
struct SMemC { float comb[4][16][64]; float lsum[4][16]; };
union SMemU { SMemS s; SMemC c; };

#define WAITVM_(n) asm volatile("s_waitcnt vmcnt(" #n ")" ::: "memory")
#define WAITVM(n) WAITVM_(n)

#define STAGE(k) do { \
    gl_lds16(asrc0 + (size_t)(k) * 32, &ladj[(k) & 3][0][0][0]); \
    gl_lds16(asrc1 + (size_t)(k) * 32, &ladj[(k) & 3][8][0][0]); \
} while (0)

#define STEPC(k, VM) do { \
    WAITVM(VM); \
    i32x4 va0 = *(const i32x4*)&ladj[(k) & 3][m][u0][0]; \
    i32x4 va1 = *(const i32x4*)&ladj[(k) & 3][m][u1][0]; \
    f32x4 ev0 = *(const f32x4*)&le2[(k) * 32 + q * 8]; \
    f32x4 ev1 = *(const f32x4*)&le2[(k) * 32 + q * 8 + 4]; \
    const short* bfp = whFw + (size_t)(k) * 2048; \
    bf16x8 wb0 = *(const bf16x8*)(bfp); \
    bf16x8 wb1 = *(const bf16x8*)(bfp + 512); \
    bf16x8 wb2 = *(const bf16x8*)(bfp + 1024); \
    bf16x8 wb3 = *(const bf16x8*)(bfp + 1536); \
    float pe[8]; \
    _Pragma("unroll") \
    for (int jj = 0; jj < 8; jj++) { \
        const int   av = (jj < 4) ? va0[jj] : va1[jj - 4]; \
        const float ej = (jj < 4) ? ev0[jj] : ev1[jj - 4]; \
        const float s  = fmaf(ej, L2E, E1v); \
        const float tt = fmaf(ALPHA, fminf(s, 0.f), fmaxf(s, 0.f)) - MiB; \
        pe[jj] = __builtin_amdgcn_exp2f(fmaf((float)av, 4000.0f, tt)); \
    } \
    union { unsigned u[4]; bf16x8 v; } au; \
    _Pragma("unroll") \
    for (int jj = 0; jj < 4; jj++) \
        au.u[jj] = __builtin_amdgcn_perm(__float_as_uint(pe[2 * jj + 1]), \
                                         __float_as_uint(pe[2 * jj]), 0x07060302u); \
    acc0 = __builtin_amdgcn_mfma_f32_16x16x32_bf16(au.v, wb0, acc0, 0, 0, 0); \
    acc1 = __builtin_amdgcn_mfma_f32_16x16x32_bf16(au.v, wb1, acc1, 0, 0, 0); \
    acc2 = __builtin_amdgcn_mfma_f32_16x16x32_bf16(au.v, wb2, acc2, 0, 0, 0); \
    acc3 = __builtin_amdgcn_mfma_f32_16x16x32_bf16(au.v, wb3, acc3, 0, 0, 0); \
    acc4 = __builtin_amdgcn_mfma_f32_16x16x32_bf16(au.v, ones, acc4, 0, 0, 0); \
} while (0)

__global__ __launch_bounds__(256, 4) void attn_kernel(
    const int* __restrict__ adj, const float* __restrict__ e1,
    const float* __restrict__ e2, const float* __restrict__ e2max,
    const short* __restrict__ whF, float* __restrict__ out)
{
    __shared__ __align__(16) SMemU sm;
    const int t = threadIdx.x, w = t >> 6, lane = t & 63;
    const int m = lane & 15, q = lane >> 4;
    const int blk = blockIdx.x;
    const int b = blk >> 7, i0 = (blk & 127) * 16;

    const float L2E = 1.4426950408889634f;
    const float e1v = e1[b * NN + i0 + m];
    float mr = e1v + e2max[b];
    mr = mr > 0.f ? mr : ALPHA * mr;          // safe per-row max bound (monotone)
    const float E1v = e1v * L2E;
    const float MiB = mr * L2E + 4000.0f;     // fold mask offset into the bound

    // staging addressing: inst p covers rows p*8+l8; unit XOR-swizzled by row
    const int l8 = lane >> 3, c7 = lane & 7;
    const int csw = (c7 ^ l8) * 4;            // swizzled col (ints)
    const int* asrc0 = adj + ((size_t)(b * NN + i0 + l8)) * NN + w * 512 + csw;
    const int* asrc1 = asrc0 + (size_t)8 * NN;
    int (*ladj)[16][8][4] = sm.s.adjs[w];
    float* le2 = sm.s.e2s[w];
    const float* e2src = e2 + b * NN + w * 512 + lane * 4;

    const short* whFw = whF + (size_t)b * (64 * 4 * 64 * 8)
                            + (size_t)(w * 16) * 2048 + lane * 8;

    f32x4 acc0 = {0.f,0.f,0.f,0.f}, acc1 = acc0, acc2 = acc0, acc3 = acc0, acc4 = acc0;
    bf16x8 ones;
#pragma unroll
    for (int jj = 0; jj < 8; jj++) ones[jj] = (short)0x3F80;   // bf16 1.0

    const int u0 = (q * 2) ^ (m & 7);         // LDS unit holding global unit q*2
    const int u1 = u0 ^ 1;

    // prologue: e2 slice + 3 steps in flight
    gl_lds16(e2src,       &le2[0]);
    gl_lds16(e2src + 256, &le2[256]);
    STAGE(0); STAGE(1); STAGE(2);

    // steady state: 13 iterations, prefetch distance 3, vmcnt(6)
#pragma unroll 1
    for (int k = 0; k < 13; k++) {
        STAGE(k + 3);
        STEPC(k, 6);
    }
    STEPC(13, 4);
    STEPC(14, 2);
    STEPC(15, 0);

    __syncthreads();                           // all private LDS reads done
    if (m == 0) {
#pragma unroll
        for (int r = 0; r < 4; r++) sm.c.lsum[w][q * 4 + r] = acc4[r];
    }
#pragma unroll
    for (int ot = 0; ot < 4; ot++) {
        f32x4 av = (ot == 0) ? acc0 : (ot == 1) ? acc1 : (ot == 2) ? acc2 : acc3;
#pragma unroll
        for (int reg = 0; reg < 4; reg++)
            sm.c.comb[w][q * 4 + reg][ot * 16 + m] = av[reg];
    }
    __syncthreads();

    const int row = t >> 4, c0 = (t & 15) * 4;
    f32x4 sum = *(const f32x4*)&sm.c.comb[0][row][c0];
#pragma unroll
    for (int ww = 1; ww < 4; ww++) {
        f32x4 sv = *(const f32x4*)&sm.c.comb[ww][row][c0];
        sum.x += sv.x; sum.y += sv.y; sum.z += sv.z; sum.w += sv.w;
    }
    float l = sm.c.lsum[0][row] + sm.c.lsum[1][row] + sm.c.lsum[2][row] + sm.c.lsum[3][row];
    l = fmaxf(l, 1e-30f);
    const float rl = 1.f / l;
    f32x4 res;
    float vr[4] = { sum.x * rl, sum.y * rl, sum.z * rl, sum.w * rl };
#pragma unroll
    for (int kk = 0; kk < 4; kk++)
        res[kk] = vr[kk] > 0.f ? vr[kk] : (__expf(vr[kk]) - 1.f);
    *(f32x4*)&out[((size_t)(b * NN + i0 + row)) * FO + c0] = res;
}

extern "C" void kernel_launch(void* const* d_in, const int* in_sizes, int n_in,
                              void* d_out, int out_size, void* d_ws, size_t ws_size,
                              hipStream_t stream) {
    const float* h   = (const float*)d_in[0];
    const int*   adj = (const int*)d_in[1];
    const float* W   = (const float*)d_in[2];
    const float* a   = (const float*)d_in[3];
    float* out = (float*)d_out;

    char* ws = (char*)d_ws;
    short* whF = (short*)ws;                                   // 2 MB
    size_t off = (size_t)BB * 64 * 4 * 64 * 8 * sizeof(short);
    float* e1  = (float*)(ws + off);  off += (size_t)BB * NN * 4;
    float* e2  = (float*)(ws + off);  off += (size_t)BB * NN * 4;
    float* e2m = (float*)(ws + off);

    wh_kernel<<<(BB * NN) / 32, 256, 0, stream>>>(h, W, a, e1, e2, whF);
    e2max_kernel<<<BB, 256, 0, stream>>>(e2, e2m);
    attn_kernel<<<BB * (NN / 16), 256, 0, stream>>>(adj, e1, e2, e2m, whF, out);
}

// Round 4
// 219.952 us; speedup vs baseline: 1.0108x; 1.0108x over previous
//
#include <hip/hip_runtime.h>
#include <hip/hip_bf16.h>

#define BB 8
#define NN 2048
#define FIN 128
#define FO 64
#define ALPHA 0.2f

typedef __attribute__((ext_vector_type(8))) short bf16x8;
typedef __attribute__((ext_vector_type(4))) float f32x4;
typedef __attribute__((ext_vector_type(4))) int i32x4;

typedef __attribute__((address_space(1))) const void gvoid;
typedef __attribute__((address_space(3))) void lvoid;

__device__ inline void gl_lds16(const void* g, void* l) {
    // async global->LDS DMA, 16B/lane; LDS dest = wave-uniform base + lane*16
    __builtin_amdgcn_global_load_lds((gvoid*)g, (lvoid*)l, 16, 0, 0);
}

__device__ inline short f2bf(float x) {
    unsigned u = __float_as_uint(x);
    u += 0x7fffu + ((u >> 16) & 1u);   // RNE
    return (short)(u >> 16);
}

// ---------------- Kernel A: Wh = h@W; whF in MFMA B-fragment layout ----------
// whF[b][jc][ot][L][8]: lane L holds Wh[b][j=jc*32+(L>>4)*8+jj][o=ot*16+(L&15)]
__global__ __launch_bounds__(256) void wh_kernel(
    const float* __restrict__ h, const float* __restrict__ W,
    const float* __restrict__ a, float* __restrict__ e1, float* __restrict__ e2,
    short* __restrict__ whF)
{
    __shared__ float hs[32][FIN];
    const int r0 = blockIdx.x * 32;
    const int t = threadIdx.x;
    const float4* hsrc = (const float4*)(h + (size_t)r0 * FIN);
    float4* hdst = (float4*)(&hs[0][0]);
#pragma unroll
    for (int k = 0; k < 4; k++) hdst[t + 256 * k] = hsrc[t + 256 * k];
    __syncthreads();

    const int o = t & 63;
    const int wv = t >> 6;
    float acc[8];
#pragma unroll
    for (int rr = 0; rr < 8; rr++) acc[rr] = 0.f;

    for (int f = 0; f < FIN; f += 4) {
        const float w0 = W[(f + 0) * FO + o];
        const float w1 = W[(f + 1) * FO + o];
        const float w2 = W[(f + 2) * FO + o];
        const float w3 = W[(f + 3) * FO + o];
#pragma unroll
        for (int rr = 0; rr < 8; rr++) {
            float4 hv = *(const float4*)&hs[wv * 8 + rr][f];
            acc[rr] = fmaf(hv.x, w0, acc[rr]);
            acc[rr] = fmaf(hv.y, w1, acc[rr]);
            acc[rr] = fmaf(hv.z, w2, acc[rr]);
            acc[rr] = fmaf(hv.w, w3, acc[rr]);
        }
    }

    const int b   = r0 / NN;
    const int ib0 = r0 - b * NN;
    const int ibb = ib0 + wv * 8;
    const int jc  = ibb >> 5;
    const int qq  = (ibb >> 3) & 3;
    const int ot  = o >> 4, mm = o & 15;
    const int L   = mm + qq * 16;
    bf16x8 frag;
#pragma unroll
    for (int rr = 0; rr < 8; rr++) frag[rr] = f2bf(acc[rr]);
    *(bf16x8*)(whF + ((((size_t)(b * 64 + jc) * 4 + ot) * 64 + L) * 8)) = frag;

    const float a1 = a[o], a2 = a[FO + o];
#pragma unroll
    for (int rr = 0; rr < 8; rr++) {
        float v1 = acc[rr] * a1, v2 = acc[rr] * a2;
#pragma unroll
        for (int msk = 32; msk >= 1; msk >>= 1) {
            v1 += __shfl_xor(v1, msk, 64);
            v2 += __shfl_xor(v2, msk, 64);
        }
        if (o == 0) { e1[r0 + wv * 8 + rr] = v1; e2[r0 + wv * 8 + rr] = v2; }
    }
}

// ---------------- Kernel A2: e2max per batch --------------------------------
__global__ __launch_bounds__(256) void e2max_kernel(
    const float* __restrict__ e2, float* __restrict__ e2max)
{
    const int b = blockIdx.x;
    const int t = threadIdx.x;
    float m = -1e30f;
    for (int j = t; j < NN; j += 256) m = fmaxf(m, e2[b * NN + j]);
#pragma unroll
    for (int k = 32; k >= 1; k >>= 1) m = fmaxf(m, __shfl_xor(m, k, 64));
    __shared__ float red[4];
    if ((t & 63) == 0) red[t >> 6] = m;
    __syncthreads();
    if (t == 0) e2max[b] = fmaxf(fmaxf(red[0], red[1]), fmaxf(red[2], red[3]));
}

// ---------------- Kernel B: barrier-free pipelined fused attention ----------
// Per-wave private j-stripe. VMEM issue order pinned per iteration:
//   [ W(k+2) regs x4 | S(k+3) gl_lds x2 | vmcnt(18) | ds_read | compute W(k) ]
// In-order vmcnt: if S(k) outstanding, >=20 ops outstanding > 18 -> forced.
// Compiler's own wait for W(k) is vmcnt(14): stages k+1..k+3 stay in flight.
struct SMemS {
    int   adjs[4][4][16][8][4];   // [wave][buf][row][unit16B][4 ints] = 32 KB
    float e2s[4][512];            // 8 KB
};
struct SMemC { float comb[4][16][64]; float lsum[4][16]; };
union SMemU { SMemS s; SMemC c; };

struct WFrag { bf16x8 f0, f1, f2, f3; };

#define CFENCE asm volatile("" ::: "memory")
#define WAITVM_(n) asm volatile("s_waitcnt vmcnt(" #n ")" ::: "memory")
#define WAITVM(n) WAITVM_(n)

#define STAGE(k) do { \
    gl_lds16(asrc0 + (size_t)(k) * 32, &ladj[(k) & 3][0][0][0]); \
    gl_lds16(asrc1 + (size_t)(k) * 32, &ladj[(k) & 3][8][0][0]); \
    CFENCE; \
} while (0)

#define WLOAD(dst, k) do { \
    const short* bfp = whFw + (size_t)(k) * 2048; \
    dst.f0 = *(const bf16x8*)(bfp); \
    dst.f1 = *(const bf16x8*)(bfp + 512); \
    dst.f2 = *(const bf16x8*)(bfp + 1024); \
    dst.f3 = *(const bf16x8*)(bfp + 1536); \
    CFENCE; \
} while (0)

#define STEPC(k, VM, WF) do { \
    WAITVM(VM); \
    i32x4 va0 = *(const i32x4*)&ladj[(k) & 3][m][u0][0]; \
    i32x4 va1 = *(const i32x4*)&ladj[(k) & 3][m][u1][0]; \
    f32x4 ev0 = *(const f32x4*)&le2[(k) * 32 + q * 8]; \
    f32x4 ev1 = *(const f32x4*)&le2[(k) * 32 + q * 8 + 4]; \
    float pe[8]; \
    _Pragma("unroll") \
    for (int jj = 0; jj < 8; jj++) { \
        const int   av = (jj < 4) ? va0[jj] : va1[jj - 4]; \
        const float ej = (jj < 4) ? ev0[jj] : ev1[jj - 4]; \
        const float s  = fmaf(ej, L2E, E1v); \
        const float lk = fmaxf(s, ALPHA * s); \
        pe[jj] = __builtin_amdgcn_exp2f(lk + fmaf((float)av, 4000.0f, negMiB)); \
    } \
    union { unsigned u[4]; bf16x8 v; } au; \
    _Pragma("unroll") \
    for (int jj = 0; jj < 4; jj++) \
        au.u[jj] = __builtin_amdgcn_perm(__float_as_uint(pe[2 * jj + 1]), \
                                         __float_as_uint(pe[2 * jj]), 0x07060302u); \
    acc0 = __builtin_amdgcn_mfma_f32_16x16x32_bf16(au.v, WF.f0, acc0, 0, 0, 0); \
    acc1 = __builtin_amdgcn_mfma_f32_16x16x32_bf16(au.v, WF.f1, acc1, 0, 0, 0); \
    acc2 = __builtin_amdgcn_mfma_f32_16x16x32_bf16(au.v, WF.f2, acc2, 0, 0, 0); \
    acc3 = __builtin_amdgcn_mfma_f32_16x16x32_bf16(au.v, WF.f3, acc3, 0, 0, 0); \
    acc4 = __builtin_amdgcn_mfma_f32_16x16x32_bf16(au.v, ones, acc4, 0, 0, 0); \
} while (0)

__global__ __launch_bounds__(256) void attn_kernel(
    const int* __restrict__ adj, const float* __restrict__ e1,
    const float* __restrict__ e2, const float* __restrict__ e2max,
    const short* __restrict__ whF, float* __restrict__ out)
{
    __shared__ __align__(16) SMemU sm;
    const int t = threadIdx.x, w = t >> 6, lane = t & 63;
    const int m = lane & 15, q = lane >> 4;
    const int blk = blockIdx.x;
    const int b = blk >> 7, i0 = (blk & 127) * 16;

    const float L2E = 1.4426950408889634f;
    const float e1v = e1[b * NN + i0 + m];
    float mr = e1v + e2max[b];
    mr = mr > 0.f ? mr : ALPHA * mr;          // safe per-row max bound (monotone)
    const float E1v = e1v * L2E;
    const float negMiB = -(mr * L2E + 4000.0f);

    const int l8 = lane >> 3, c7 = lane & 7;
    const int csw = (c7 ^ l8) * 4;            // XOR-swizzled 16B unit by row
    const int* asrc0 = adj + ((size_t)(b * NN + i0 + l8)) * NN + w * 512 + csw;
    const int* asrc1 = asrc0 + (size_t)8 * NN;
    int (*ladj)[16][8][4] = sm.s.adjs[w];
    float* le2 = sm.s.e2s[w];
    const float* e2src = e2 + b * NN + w * 512 + lane * 4;

    const short* whFw = whF + (size_t)b * (64 * 4 * 64 * 8)
                            + (size_t)(w * 16) * 2048 + lane * 8;

    f32x4 acc0 = {0.f,0.f,0.f,0.f}, acc1 = acc0, acc2 = acc0, acc3 = acc0, acc4 = acc0;
    bf16x8 ones;
#pragma unroll
    for (int jj = 0; jj < 8; jj++) ones[jj] = (short)0x3F80;   // bf16 1.0

    const int u0 = (q * 2) ^ (m & 7);
    const int u1 = u0 ^ 1;

    // prologue (order pinned by CFENCEs): e2, S0, S1, S2, W0, W1
    gl_lds16(e2src,       &le2[0]);
    gl_lds16(e2src + 256, &le2[256]);
    CFENCE;
    STAGE(0); STAGE(1); STAGE(2);
    WFrag W0f, W1f;
    WLOAD(W0f, 0); WLOAD(W1f, 1);

    // steady state: slot A_k = [W(k+2), S(k+3), vmcnt(18), compute k]
#pragma unroll 1
    for (int k = 0; k < 12; k += 2) {
        WFrag Wa; WLOAD(Wa, k + 2); STAGE(k + 3); STEPC(k, 18, W0f); W0f = Wa;
        WFrag Wb; WLOAD(Wb, k + 3); STAGE(k + 4); STEPC(k + 1, 18, W1f); W1f = Wb;
    }
    { WFrag Wa; WLOAD(Wa, 14); STAGE(15); STEPC(12, 18, W0f); W0f = Wa; }
    { WFrag Wb; WLOAD(Wb, 15);            STEPC(13, 16, W1f); W1f = Wb; }
    STEPC(14, 10, W0f);
    STEPC(15,  4, W1f);

    __syncthreads();                           // all private LDS reads done
    if (m == 0) {
#pragma unroll
        for (int r = 0; r < 4; r++) sm.c.lsum[w][q * 4 + r] = acc4[r];
    }
#pragma unroll
    for (int ot = 0; ot < 4; ot++) {
        f32x4 av = (ot == 0) ? acc0 : (ot == 1) ? acc1 : (ot == 2) ? acc2 : acc3;
#pragma unroll
        for (int reg = 0; reg < 4; reg++)
            sm.c.comb[w][q * 4 + reg][ot * 16 + m] = av[reg];
    }
    __syncthreads();

    const int row = t >> 4, c0 = (t & 15) * 4;
    f32x4 sum = *(const f32x4*)&sm.c.comb[0][row][c0];
#pragma unroll
    for (int ww = 1; ww < 4; ww++) {
        f32x4 sv = *(const f32x4*)&sm.c.comb[ww][row][c0];
        sum.x += sv.x; sum.y += sv.y; sum.z += sv.z; sum.w += sv.w;
    }
    float l = sm.c.lsum[0][row] + sm.c.lsum[1][row] + sm.c.lsum[2][row] + sm.c.lsum[3][row];
    l = fmaxf(l, 1e-30f);
    const float rl = 1.f / l;
    f32x4 res;
    float vr[4] = { sum.x * rl, sum.y * rl, sum.z * rl, sum.w * rl };
#pragma unroll
    for (int kk = 0; kk < 4; kk++)
        res[kk] = vr[kk] > 0.f ? vr[kk] : (__expf(vr[kk]) - 1.f);
    *(f32x4*)&out[((size_t)(b * NN + i0 + row)) * FO + c0] = res;
}

extern "C" void kernel_launch(void* const* d_in, const int* in_sizes, int n_in,
                              void* d_out, int out_size, void* d_ws, size_t ws_size,
                              hipStream_t stream) {
    const float* h   = (const float*)d_in[0];
    const int*   adj = (const int*)d_in[1];
    const float* W   = (const float*)d_in[2];
    const float* a   = (const float*)d_in[3];
    float* out = (float*)d_out;

    char* ws = (char*)d_ws;
    short* whF = (short*)ws;                                   // 2 MB
    size_t off = (size_t)BB * 64 * 4 * 64 * 8 * sizeof(short);
    float* e1  = (float*)(ws + off);  off += (size_t)BB * NN * 4;
    float* e2  = (float*)(ws + off);  off += (size_t)BB * NN * 4;
    float* e2m = (float*)(ws + off);

    wh_kernel<<<(BB * NN) / 32, 256, 0, stream>>>(h, W, a, e1, e2, whF);
    e2max_kernel<<<BB, 256, 0, stream>>>(e2, e2m);
    attn_kernel<<<BB * (NN / 16), 256, 0, stream>>>(adj, e1, e2, e2m, whF, out);
}

// Round 5
// 219.344 us; speedup vs baseline: 1.0136x; 1.0028x over previous
//
#include <hip/hip_runtime.h>
#include <hip/hip_bf16.h>

#define BB 8
#define NN 2048
#define FIN 128
#define FO 64
#define ALPHA 0.2f

typedef __attribute__((ext_vector_type(8))) short bf16x8;
typedef __attribute__((ext_vector_type(4))) float f32x4;
typedef __attribute__((ext_vector_type(4))) int i32x4;

typedef __attribute__((address_space(1))) const void gvoid;
typedef __attribute__((address_space(3))) void lvoid;

__device__ inline void gl_lds16(const void* g, void* l) {
    // async global->LDS DMA, 16B/lane; LDS dest = wave-uniform base + lane*16
    __builtin_amdgcn_global_load_lds((gvoid*)g, (lvoid*)l, 16, 0, 0);
}

__device__ inline short f2bf(float x) {
    unsigned u = __float_as_uint(x);
    u += 0x7fffu + ((u >> 16) & 1u);   // RNE
    return (short)(u >> 16);
}

// ---------------- Kernel A: Wh = h@W; whF in MFMA B-fragment layout ----------
// whF[b][jc][ot][L][8]: lane L holds Wh[b][j=jc*32+(L>>4)*8+jj][o=ot*16+(L&15)]
__global__ __launch_bounds__(256) void wh_kernel(
    const float* __restrict__ h, const float* __restrict__ W,
    const float* __restrict__ a, float* __restrict__ e1, float* __restrict__ e2,
    short* __restrict__ whF)
{
    __shared__ float hs[32][FIN];
    const int r0 = blockIdx.x * 32;
    const int t = threadIdx.x;
    const float4* hsrc = (const float4*)(h + (size_t)r0 * FIN);
    float4* hdst = (float4*)(&hs[0][0]);
#pragma unroll
    for (int k = 0; k < 4; k++) hdst[t + 256 * k] = hsrc[t + 256 * k];
    __syncthreads();

    const int o = t & 63;
    const int wv = t >> 6;
    float acc[8];
#pragma unroll
    for (int rr = 0; rr < 8; rr++) acc[rr] = 0.f;

    for (int f = 0; f < FIN; f += 4) {
        const float w0 = W[(f + 0) * FO + o];
        const float w1 = W[(f + 1) * FO + o];
        const float w2 = W[(f + 2) * FO + o];
        const float w3 = W[(f + 3) * FO + o];
#pragma unroll
        for (int rr = 0; rr < 8; rr++) {
            float4 hv = *(const float4*)&hs[wv * 8 + rr][f];
            acc[rr] = fmaf(hv.x, w0, acc[rr]);
            acc[rr] = fmaf(hv.y, w1, acc[rr]);
            acc[rr] = fmaf(hv.z, w2, acc[rr]);
            acc[rr] = fmaf(hv.w, w3, acc[rr]);
        }
    }

    const int b   = r0 / NN;
    const int ib0 = r0 - b * NN;
    const int ibb = ib0 + wv * 8;
    const int jc  = ibb >> 5;
    const int qq  = (ibb >> 3) & 3;
    const int ot  = o >> 4, mm = o & 15;
    const int L   = mm + qq * 16;
    bf16x8 frag;
#pragma unroll
    for (int rr = 0; rr < 8; rr++) frag[rr] = f2bf(acc[rr]);
    *(bf16x8*)(whF + ((((size_t)(b * 64 + jc) * 4 + ot) * 64 + L) * 8)) = frag;

    const float a1 = a[o], a2 = a[FO + o];
#pragma unroll
    for (int rr = 0; rr < 8; rr++) {
        float v1 = acc[rr] * a1, v2 = acc[rr] * a2;
#pragma unroll
        for (int msk = 32; msk >= 1; msk >>= 1) {
            v1 += __shfl_xor(v1, msk, 64);
            v2 += __shfl_xor(v2, msk, 64);
        }
        if (o == 0) { e1[r0 + wv * 8 + rr] = v1; e2[r0 + wv * 8 + rr] = v2; }
    }
}

// ---------------- Kernel A2: e2max per batch --------------------------------
__global__ __launch_bounds__(256) void e2max_kernel(
    const float* __restrict__ e2, float* __restrict__ e2max)
{
    const int b = blockIdx.x;
    const int t = threadIdx.x;
    float m = -1e30f;
    for (int j = t; j < NN; j += 256) m = fmaxf(m, e2[b * NN + j]);
#pragma unroll
    for (int k = 32; k >= 1; k >>= 1) m = fmaxf(m, __shfl_xor(m, k, 64));
    __shared__ float red[4];
    if ((t & 63) == 0) red[t >> 6] = m;
    __syncthreads();
    if (t == 0) e2max[b] = fmaxf(fmaxf(red[0], red[1]), fmaxf(red[2], red[3]));
}

// ---------------- Kernel B: T=2 i-tile-reuse pipelined fused attention ------
// Block = (b, 32 rows = two 16-row A-tiles); wave w owns j-stripe [w*512,+512).
// Each W-fragment load feeds BOTH A-tiles (halves whF re-read traffic).
// VMEM issue order pinned: [W(k+2)x4 | S(k+3)x4 | vmcnt(20) | compute k].
struct SMemS {
    int   adjs[4][4][2][16][8][4];  // [wave][buf][tile][row][unit16B][4] = 64 KB
    float e2s[4][512];              // 8 KB
};
struct SMemC { float comb[4][2][16][64]; float lsum[4][2][16]; };
union SMemU { SMemS s; SMemC c; };

struct WFrag { bf16x8 f0, f1, f2, f3; };

#define CFENCE asm volatile("" ::: "memory")
#define WAITVM_(n) asm volatile("s_waitcnt vmcnt(" #n ")" ::: "memory")
#define WAITVM(n) WAITVM_(n)

#define STAGE(k) do { \
    const int bf_ = (k) & 3; \
    gl_lds16(asrc0 + (size_t)(k) * 32, &ladj[bf_][0][0][0][0]); \
    gl_lds16(asrc1 + (size_t)(k) * 32, &ladj[bf_][0][8][0][0]); \
    gl_lds16(asrc2 + (size_t)(k) * 32, &ladj[bf_][1][0][0][0]); \
    gl_lds16(asrc3 + (size_t)(k) * 32, &ladj[bf_][1][8][0][0]); \
    CFENCE; \
} while (0)

#define WLOAD(dst, k) do { \
    const short* bfp = whFw + (size_t)(k) * 2048; \
    dst.f0 = *(const bf16x8*)(bfp); \
    dst.f1 = *(const bf16x8*)(bfp + 512); \
    dst.f2 = *(const bf16x8*)(bfp + 1024); \
    dst.f3 = *(const bf16x8*)(bfp + 1536); \
    CFENCE; \
} while (0)

#define SCORE8(AU, VA0, VA1, E1C, NMB) do { \
    float pe[8]; \
    _Pragma("unroll") \
    for (int jj = 0; jj < 8; jj++) { \
        const int   av = (jj < 4) ? VA0[jj] : VA1[jj - 4]; \
        const float ej = (jj < 4) ? ev0[jj] : ev1[jj - 4]; \
        const float s  = fmaf(ej, L2E, E1C); \
        const float lk = fmaxf(s, ALPHA * s); \
        pe[jj] = __builtin_amdgcn_exp2f(lk + fmaf((float)av, 4000.0f, NMB)); \
    } \
    _Pragma("unroll") \
    for (int jj = 0; jj < 4; jj++) \
        AU.u[jj] = __builtin_amdgcn_perm(__float_as_uint(pe[2 * jj + 1]), \
                                         __float_as_uint(pe[2 * jj]), 0x07060302u); \
} while (0)

#define STEPC(k, VM, WF) do { \
    WAITVM(VM); \
    const int bf_ = (k) & 3; \
    i32x4 va00 = *(const i32x4*)&ladj[bf_][0][m][u0][0]; \
    i32x4 va01 = *(const i32x4*)&ladj[bf_][0][m][u1][0]; \
    i32x4 va10 = *(const i32x4*)&ladj[bf_][1][m][u0][0]; \
    i32x4 va11 = *(const i32x4*)&ladj[bf_][1][m][u1][0]; \
    f32x4 ev0 = *(const f32x4*)&le2[(k) * 32 + q * 8]; \
    f32x4 ev1 = *(const f32x4*)&le2[(k) * 32 + q * 8 + 4]; \
    union { unsigned u[4]; bf16x8 v; } au0, au1; \
    SCORE8(au0, va00, va01, E1v0, negMiB0); \
    SCORE8(au1, va10, va11, E1v1, negMiB1); \
    acc00 = __builtin_amdgcn_mfma_f32_16x16x32_bf16(au0.v, WF.f0, acc00, 0, 0, 0); \
    acc01 = __builtin_amdgcn_mfma_f32_16x16x32_bf16(au0.v, WF.f1, acc01, 0, 0, 0); \
    acc02 = __builtin_amdgcn_mfma_f32_16x16x32_bf16(au0.v, WF.f2, acc02, 0, 0, 0); \
    acc03 = __builtin_amdgcn_mfma_f32_16x16x32_bf16(au0.v, WF.f3, acc03, 0, 0, 0); \
    acc04 = __builtin_amdgcn_mfma_f32_16x16x32_bf16(au0.v, ones, acc04, 0, 0, 0); \
    acc10 = __builtin_amdgcn_mfma_f32_16x16x32_bf16(au1.v, WF.f0, acc10, 0, 0, 0); \
    acc11 = __builtin_amdgcn_mfma_f32_16x16x32_bf16(au1.v, WF.f1, acc11, 0, 0, 0); \
    acc12 = __builtin_amdgcn_mfma_f32_16x16x32_bf16(au1.v, WF.f2, acc12, 0, 0, 0); \
    acc13 = __builtin_amdgcn_mfma_f32_16x16x32_bf16(au1.v, WF.f3, acc13, 0, 0, 0); \
    acc14 = __builtin_amdgcn_mfma_f32_16x16x32_bf16(au1.v, ones, acc14, 0, 0, 0); \
} while (0)

__global__ __launch_bounds__(256) void attn_kernel(
    const int* __restrict__ adj, const float* __restrict__ e1,
    const float* __restrict__ e2, const float* __restrict__ e2max,
    const short* __restrict__ whF, float* __restrict__ out)
{
    __shared__ __align__(16) SMemU sm;
    const int t = threadIdx.x, w = t >> 6, lane = t & 63;
    const int m = lane & 15, q = lane >> 4;
    const int blk = blockIdx.x;
    const int b = blk >> 6, i0 = (blk & 63) * 32;

    const float L2E = 1.4426950408889634f;
    const float e2m = e2max[b];
    const float e1v0 = e1[b * NN + i0 + m];
    const float e1v1 = e1[b * NN + i0 + 16 + m];
    float mr0 = e1v0 + e2m; mr0 = mr0 > 0.f ? mr0 : ALPHA * mr0;
    float mr1 = e1v1 + e2m; mr1 = mr1 > 0.f ? mr1 : ALPHA * mr1;
    const float E1v0 = e1v0 * L2E, E1v1 = e1v1 * L2E;
    const float negMiB0 = -(mr0 * L2E + 4000.0f);
    const float negMiB1 = -(mr1 * L2E + 4000.0f);

    const int l8 = lane >> 3, c7 = lane & 7;
    const int csw = (c7 ^ l8) * 4;            // XOR-swizzled 16B unit by row
    const int* asrc0 = adj + ((size_t)(b * NN + i0 + l8)) * NN + w * 512 + csw;
    const int* asrc1 = asrc0 + (size_t)8 * NN;
    const int* asrc2 = asrc0 + (size_t)16 * NN;
    const int* asrc3 = asrc0 + (size_t)24 * NN;
    int (*ladj)[2][16][8][4] = sm.s.adjs[w];
    float* le2 = sm.s.e2s[w];
    const float* e2src = e2 + b * NN + w * 512 + lane * 4;

    const short* whFw = whF + (size_t)b * (64 * 4 * 64 * 8)
                            + (size_t)(w * 16) * 2048 + lane * 8;

    f32x4 z = {0.f,0.f,0.f,0.f};
    f32x4 acc00 = z, acc01 = z, acc02 = z, acc03 = z, acc04 = z;
    f32x4 acc10 = z, acc11 = z, acc12 = z, acc13 = z, acc14 = z;
    bf16x8 ones;
#pragma unroll
    for (int jj = 0; jj < 8; jj++) ones[jj] = (short)0x3F80;   // bf16 1.0

    const int u0 = (q * 2) ^ (m & 7);
    const int u1 = u0 ^ 1;

    // prologue (order pinned): e2 DMA, S0, S1, S2, W0, W1
    gl_lds16(e2src,       &le2[0]);
    gl_lds16(e2src + 256, &le2[256]);
    CFENCE;
    STAGE(0); STAGE(1); STAGE(2);
    WFrag W0f, W1f;
    WLOAD(W0f, 0); WLOAD(W1f, 1);

    // steady: per iter issue W(k+2), S(k+3); force S(k) via vmcnt(20)
#pragma unroll 1
    for (int k = 0; k < 12; k += 2) {
        WFrag Wa; WLOAD(Wa, k + 2); STAGE(k + 3); STEPC(k, 20, W0f); W0f = Wa;
        WFrag Wb; WLOAD(Wb, k + 3); STAGE(k + 4); STEPC(k + 1, 20, W1f); W1f = Wb;
    }
    { WFrag Wa; WLOAD(Wa, 14); STAGE(15); STEPC(12, 20, W0f); W0f = Wa; }
    { WFrag Wb; WLOAD(Wb, 15);            STEPC(13, 20, W1f); W1f = Wb; }
    STEPC(14, 12, W0f);
    STEPC(15,  4, W1f);

    __syncthreads();                           // all private LDS reads done
    if (m == 0) {
#pragma unroll
        for (int r = 0; r < 4; r++) {
            sm.c.lsum[w][0][q * 4 + r] = acc04[r];
            sm.c.lsum[w][1][q * 4 + r] = acc14[r];
        }
    }
#pragma unroll
    for (int ot = 0; ot < 4; ot++) {
        f32x4 a0 = (ot == 0) ? acc00 : (ot == 1) ? acc01 : (ot == 2) ? acc02 : acc03;
        f32x4 a1 = (ot == 0) ? acc10 : (ot == 1) ? acc11 : (ot == 2) ? acc12 : acc13;
#pragma unroll
        for (int reg = 0; reg < 4; reg++) {
            sm.c.comb[w][0][q * 4 + reg][ot * 16 + m] = a0[reg];
            sm.c.comb[w][1][q * 4 + reg][ot * 16 + m] = a1[reg];
        }
    }
    __syncthreads();

#pragma unroll
    for (int it = 0; it < 2; it++) {
        const int idx = t + it * 256;          // 0..511 f32x4 units
        const int row = idx >> 4;              // 0..31
        const int tl = row >> 4, r16 = row & 15;
        const int c0 = (idx & 15) * 4;
        f32x4 sum = *(const f32x4*)&sm.c.comb[0][tl][r16][c0];
#pragma unroll
        for (int ww = 1; ww < 4; ww++) {
            f32x4 sv = *(const f32x4*)&sm.c.comb[ww][tl][r16][c0];
            sum.x += sv.x; sum.y += sv.y; sum.z += sv.z; sum.w += sv.w;
        }
        float l = sm.c.lsum[0][tl][r16] + sm.c.lsum[1][tl][r16]
                + sm.c.lsum[2][tl][r16] + sm.c.lsum[3][tl][r16];
        l = fmaxf(l, 1e-30f);
        const float rl = 1.f / l;
        f32x4 res;
        float vr[4] = { sum.x * rl, sum.y * rl, sum.z * rl, sum.w * rl };
#pragma unroll
        for (int kk = 0; kk < 4; kk++)
            res[kk] = vr[kk] > 0.f ? vr[kk] : (__expf(vr[kk]) - 1.f);
        *(f32x4*)&out[((size_t)(b * NN + i0 + row)) * FO + c0] = res;
    }
}

extern "C" void kernel_launch(void* const* d_in, const int* in_sizes, int n_in,
                              void* d_out, int out_size, void* d_ws, size_t ws_size,
                              hipStream_t stream) {
    const float* h   = (const float*)d_in[0];
    const int*   adj = (const int*)d_in[1];
    const float* W   = (const float*)d_in[2];
    const float* a   = (const float*)d_in[3];
    float* out = (float*)d_out;

    char* ws = (char*)d_ws;
    short* whF = (short*)ws;                                   // 2 MB
    size_t off = (size_t)BB * 64 * 4 * 64 * 8 * sizeof(short);
    float* e1  = (float*)(ws + off);  off += (size_t)BB * NN * 4;
    float* e2  = (float*)(ws + off);  off += (size_t)BB * NN * 4;
    float* e2m = (float*)(ws + off);

    wh_kernel<<<(BB * NN) / 32, 256, 0, stream>>>(h, W, a, e1, e2, whF);
    e2max_kernel<<<BB, 256, 0, stream>>>(e2, e2m);
    attn_kernel<<<BB * (NN / 32), 256, 0, stream>>>(adj, e1, e2, e2m, whF, out);
}